// Round 8
// baseline (538.627 us; speedup 1.0000x reference)
//
#include <hip/hip_runtime.h>
#include <hip/hip_bf16.h>

// Problem constants (fixed by setup_inputs)
#define T_TOK 2048
#define DDIM  2048
#define IDIM  2816
#define NE    8
#define NPAIR (T_TOK*2)      // 4096 (token, k) pairs
#define GU_N  (2*IDIM)       // 5632

// Weight chunking (bf16 pre-dequant buffers reuse dead ws regions)
#define CH13  1408           // W13 rows per chunk (4 chunks x 11 n-blocks)
#define NCH13 4
#define CH2   1024           // W2 rows per chunk (2 chunks x 8 n-blocks)
#define NCH2  2

typedef __bf16  bf16x8 __attribute__((ext_vector_type(8)));
typedef float   f32x4  __attribute__((ext_vector_type(4)));
typedef int     int4v  __attribute__((ext_vector_type(4)));
typedef unsigned int uint4v __attribute__((ext_vector_type(4)));

// ws layout (bytes)
#define OFF_A   (64*1024)
#define OFF_GU  (OFF_A  + (size_t)NPAIR*DDIM*2)   // gu: 46.14 MB bf16 (linear)
#define OFF_H   (OFF_GU + (size_t)NPAIR*GU_N*2)   // h: 23.07 MB bf16 (pre-swizzled)
#define OFF_YP  (OFF_H  + (size_t)NPAIR*IDIM*2)   // yp: 32 MB f32
// Overlays (stream-serial lifetimes):
//   W13b chunk (46.14 MB) at OFF_H: spans h+part of yp — both dead during the
//     deq13/gemm1 phase (h written by act AFTER gemm1; yp written by gemm2).
//   W2b chunk (46.14 MB) at OFF_GU: gu is dead after act.
// Total ws usage unchanged from the proven ~117 MB layout.

__device__ __forceinline__ unsigned short f2bf(float f) {
    __hip_bfloat16 h = __float2bfloat16(f);
    return __builtin_bit_cast(unsigned short, h);
}
__device__ __forceinline__ float bf2f(unsigned short u) {
    unsigned int x = ((unsigned int)u) << 16;
    return __builtin_bit_cast(float, x);
}
__device__ __forceinline__ unsigned int pack2bf(float lo, float hi) {
    return ((unsigned int)f2bf(hi) << 16) | (unsigned int)f2bf(lo);
}
// async global->LDS, 16B per lane; LDS dest must be wave-uniform-base + lane*16
__device__ __forceinline__ void gload_lds16(const void* g, void* l) {
    __builtin_amdgcn_global_load_lds(
        (const __attribute__((address_space(1))) void*)g,
        (__attribute__((address_space(3))) void*)l, 16, 0, 0);
}

// ---------------- routing: stable compaction of 4096 pairs by expert ---------
// meta: [0..7]=cnt, [8..15]=off (exclusive prefix), [64..64+4095]=list (pair idx)
__global__ void route_kernel(const int* __restrict__ ids, int* __restrict__ meta) {
    __shared__ int histL[NE][256];
    __shared__ int totals[NE];
    __shared__ int offsS[NE];
    const int tid = threadIdx.x;
    for (int e = 0; e < NE; ++e) histL[e][tid] = 0;
    for (int j = 0; j < 16; ++j) {
        int id = ids[tid*16 + j];
        histL[id][tid]++;
    }
    __syncthreads();
    if (tid < NE) {
        int run = 0;
        for (int i = 0; i < 256; ++i) { int v = histL[tid][i]; histL[tid][i] = run; run += v; }
        totals[tid] = run;
    }
    __syncthreads();
    if (tid == 0) {
        int run = 0;
        for (int e = 0; e < NE; ++e) {
            offsS[e] = run;
            meta[e] = totals[e];
            meta[8+e] = run;
            run += totals[e];
        }
    }
    __syncthreads();
    for (int j = 0; j < 16; ++j) {
        int p = tid*16 + j;
        int id = ids[p];
        int local = histL[id][tid];
        histL[id][tid] = local + 1;
        meta[64 + offsS[id] + local] = p;
    }
}

// ---------------- gather: x rows -> compact PRE-SWIZZLED bf16 A matrix -------
// logical col-byte cb of row r stored at (cb&~127) | ((cb&127) ^ ((r&7)<<4))
__global__ void gather_kernel(const float* __restrict__ x, const int* __restrict__ meta,
                              unsigned short* __restrict__ Aall) {
    const int r = blockIdx.x;
    const int p = meta[64 + r];
    const int t = p >> 1;
    const int c = threadIdx.x * 8;
    const float4* src = (const float4*)(x + (size_t)t*DDIM + c);
    float4 f0 = src[0], f1 = src[1];
    unsigned short o[8];
    o[0]=f2bf(f0.x); o[1]=f2bf(f0.y); o[2]=f2bf(f0.z); o[3]=f2bf(f0.w);
    o[4]=f2bf(f1.x); o[5]=f2bf(f1.y); o[6]=f2bf(f1.z); o[7]=f2bf(f1.w);
    int cb  = c * 2;
    int cbs = (cb & ~127) | ((cb & 127) ^ ((r & 7) << 4));
    *(uint4v*)((char*)Aall + (size_t)r*(DDIM*2) + cbs) = *(uint4v*)o;
}

// ---------------- deq13: int4 -> bf16, PRE-SWIZZLED chunk buffer -------------
// One block per (local row, expert). Thread c dequants k in [8c, 8c+8).
// Swizzle keyed on chunk-LOCAL row (chunk base is a multiple of 128, so
// local&7 == global&7) — matches the GEMM's ds_read XOR.
__global__ void deq13_kernel(const int* __restrict__ wp,
                             const float* __restrict__ wsc,
                             const float* __restrict__ wzp,
                             unsigned short* __restrict__ Wb, int row0) {
    const int lrow = blockIdx.x;          // 0..CH13-1
    const int e    = blockIdx.y;
    const int r    = row0 + lrow;         // global W13 row
    const int c    = threadIdx.x;         // 0..255 (covers K=2048)
    int4v p = *(const int4v*)(wp + ((size_t)e*GU_N + r)*(DDIM/2) + c*4);
    const int g = c >> 4;
    float s  = wsc[((size_t)e*GU_N + r)*(DDIM/128) + g];
    float z  = wzp[((size_t)e*GU_N + r)*(DDIM/128) + g];
    float cc = -z*s;
    unsigned int o[4];
#pragma unroll
    for (int j = 0; j < 4; ++j) {
        int v = p[j];
        float lo = (float)(v & 15);
        float hi = (float)((v >> 4) & 15);
        o[j] = pack2bf(fmaf(lo, s, cc), fmaf(hi, s, cc));
    }
    int cb  = c * 16;
    int cbs = (cb & ~127) | ((cb & 127) ^ ((lrow & 7) << 4));
    *(uint4v*)((char*)Wb + ((size_t)e*CH13 + lrow)*(DDIM*2) + cbs) = *(uint4v*)o;
}

// ---------------- deq2: same for W2 (K=2816) ---------------------------------
__global__ void deq2_kernel(const int* __restrict__ wp,
                            const float* __restrict__ wsc,
                            const float* __restrict__ wzp,
                            unsigned short* __restrict__ Wb, int row0) {
    const int lrow = blockIdx.x;          // 0..CH2-1
    const int e    = blockIdx.y;
    const int r    = row0 + lrow;         // global W2 row
    for (int c = threadIdx.x; c < IDIM/8; c += 256) {
        int4v p = *(const int4v*)(wp + ((size_t)e*DDIM + r)*(IDIM/2) + c*4);
        const int g = c >> 4;
        float s  = wsc[((size_t)e*DDIM + r)*(IDIM/128) + g];
        float z  = wzp[((size_t)e*DDIM + r)*(IDIM/128) + g];
        float cc = -z*s;
        unsigned int o[4];
#pragma unroll
        for (int j = 0; j < 4; ++j) {
            int v = p[j];
            float lo = (float)(v & 15);
            float hi = (float)((v >> 4) & 15);
            o[j] = pack2bf(fmaf(lo, s, cc), fmaf(hi, s, cc));
        }
        int cb  = c * 16;
        int cbs = (cb & ~127) | ((cb & 127) ^ ((lrow & 7) << 4));
        *(uint4v*)((char*)Wb + ((size_t)e*CH2 + lrow)*(IDIM*2) + cbs) = *(uint4v*)o;
    }
}

// ============ m97-style both-async GEMM macros (shared by gemm1/gemm2) =======
// Single 32KB buffer pair (As,Bs 16KB each) -> ~5 blocks/CU. Per K-step:
//   sync1 (readers of prev step done) ; ISSUE A+B async->LDS ; sync2 (implicit
//   vmcnt(0): DMA landed) ; MFMA.  No VALU dequant, no ds_write — the in-loop
//   DEQ was 32x-redundant across m-blocks and is now a separate streaming pass.
#define ISSUE_A(KT) do {                                                   \
    _Pragma("unroll")                                                      \
    for (int _i = 0; _i < 4; ++_i)                                         \
        gload_lds16(a_src[_i] + (size_t)(KT)*128,                          \
                    (char*)As + wv*4096 + _i*1024 + lane*16);              \
} while (0)
#define ISSUE_B(KT) do {                                                   \
    _Pragma("unroll")                                                      \
    for (int _i = 0; _i < 4; ++_i)                                         \
        gload_lds16(b_src[_i] + (size_t)(KT)*128,                          \
                    (char*)Bs + wv*4096 + _i*1024 + lane*16);              \
} while (0)

// MFMA_STEP: ds_read frags (A xor uses global-row parity base7+row; B rows are
// 128-aligned so parity is local) and accumulate
#define MFMA_STEP() do {                                                   \
    _Pragma("unroll")                                                      \
    for (int _kk = 0; _kk < 2; ++_kk) {                                    \
        bf16x8 _af[4], _bf[4];                                             \
        const int _kbyte = _kk*64 + lk*16;                                 \
        _Pragma("unroll")                                                  \
        for (int _mi = 0; _mi < 4; ++_mi) {                                \
            int _row = wm + _mi*16 + lr;                                   \
            int _b = _kbyte ^ (((_row + base7) & 7) << 4);                 \
            _af[_mi] = *(const bf16x8*)(&As[_row*64 + (_b >> 1)]);         \
        }                                                                  \
        _Pragma("unroll")                                                  \
        for (int _nj = 0; _nj < 4; ++_nj) {                                \
            int _row = wn + _nj*16 + lr;                                   \
            int _b = _kbyte ^ ((_row & 7) << 4);                           \
            _bf[_nj] = *(const bf16x8*)(&Bs[_row*64 + (_b >> 1)]);         \
        }                                                                  \
        _Pragma("unroll")                                                  \
        for (int _mi = 0; _mi < 4; ++_mi)                                  \
            _Pragma("unroll")                                              \
            for (int _nj = 0; _nj < 4; ++_nj)                              \
                acc[_mi][_nj] = __builtin_amdgcn_mfma_f32_16x16x32_bf16(   \
                    _af[_mi], _bf[_nj], acc[_mi][_nj], 0, 0, 0);           \
    }                                                                      \
} while (0)

// ---------------- GEMM1: A[4096,2048]bf16 x W13b-chunk^T (bf16) --------------
// grid (11, 32, 8); chunk covers gu columns [col0, col0+1408)
__launch_bounds__(256, 3)
__global__ void gemm1_kernel(const unsigned short* __restrict__ Aall,
                             const unsigned short* __restrict__ Wb,
                             const int* __restrict__ meta,
                             unsigned short* __restrict__ gu, int col0) {
    const int e   = blockIdx.z;
    const int cnt = meta[e];
    const int m0  = blockIdx.y * 128;
    if (m0 >= cnt) return;
    const int off = meta[8 + e];
    const int bx  = blockIdx.x;
    const int tid = threadIdx.x;

    __shared__ unsigned short As[128*64];   // 16 KB
    __shared__ unsigned short Bs[128*64];   // 16 KB

    f32x4 acc[4][4];
#pragma unroll
    for (int i = 0; i < 4; ++i)
#pragma unroll
        for (int j = 0; j < 4; ++j) acc[i][j] = (f32x4)0.0f;

    const int lane = tid & 63;
    const int wv   = tid >> 6;
    const char* a_src[4];
    const char* b_src[4];
#pragma unroll
    for (int i = 0; i < 4; ++i) {
        int lrow  = wv*32 + i*8 + (lane >> 3);
        int garow = off + m0 + lrow; if (garow > NPAIR-1) garow = NPAIR-1;
        a_src[i] = (const char*)Aall + (size_t)garow*(DDIM*2) + (lane & 7)*16;
        b_src[i] = (const char*)Wb +
                   ((size_t)e*CH13 + bx*128 + lrow)*(DDIM*2) + (lane & 7)*16;
    }
    const int base7 = (off + m0) & 7;

    const int wm = (wv >> 1) * 64, wn = (wv & 1) * 64;
    const int lr = lane & 15, lk = lane >> 4;

    const int NT = DDIM/64;   // 32
    for (int kt = 0; kt < NT; ++kt) {
        if (kt > 0) __syncthreads();
        ISSUE_A(kt);
        ISSUE_B(kt);
        __syncthreads();
        MFMA_STEP();
    }

    // epilogue: C[m][n] lane map col=lane&15, row=(lane>>4)*4+reg (m89)
#pragma unroll
    for (int mi = 0; mi < 4; ++mi)
#pragma unroll
        for (int nj = 0; nj < 4; ++nj) {
            f32x4 v = acc[mi][nj];
            int col = col0 + bx*128 + wn + nj*16 + lr;
#pragma unroll
            for (int r = 0; r < 4; ++r) {
                int row = wm + mi*16 + lk*4 + r;
                if (m0 + row < cnt)
                    gu[(size_t)(off + m0 + row)*GU_N + col] = f2bf(v[r]);
            }
        }
}

// ---------------- activation: h = silu(g)*u, written PRE-SWIZZLED ------------
__global__ void act_kernel(const unsigned short* __restrict__ gu,
                           unsigned short* __restrict__ h) {
    const int r = blockIdx.x;
    for (int c = threadIdx.x; c < IDIM/8; c += 256) {
        uint4v g8 = *(const uint4v*)(&gu[(size_t)r*GU_N + c*8]);
        uint4v u8 = *(const uint4v*)(&gu[(size_t)r*GU_N + IDIM + c*8]);
        const unsigned short* gp = (const unsigned short*)&g8;
        const unsigned short* up = (const unsigned short*)&u8;
        unsigned short o[8];
#pragma unroll
        for (int j = 0; j < 8; ++j) {
            float g = bf2f(gp[j]), u = bf2f(up[j]);
            float sg = g / (1.0f + __expf(-g));
            o[j] = f2bf(sg * u);
        }
        int cb  = c * 16;
        int cbs = (cb & ~127) | ((cb & 127) ^ ((r & 7) << 4));
        *(uint4v*)((char*)h + (size_t)r*(IDIM*2) + cbs) = *(uint4v*)o;
    }
}

// ---------------- GEMM2: h[4096,2816]bf16 x W2b-chunk^T (bf16) ---------------
// grid (8, 32, 8); chunk covers yp columns [col0, col0+1024)
__launch_bounds__(256, 3)
__global__ void gemm2_kernel(const unsigned short* __restrict__ h,
                             const unsigned short* __restrict__ Wb,
                             const float* __restrict__ tw,
                             const int* __restrict__ meta,
                             float* __restrict__ yp, int col0) {
    const int e   = blockIdx.z;
    const int cnt = meta[e];
    const int m0  = blockIdx.y * 128;
    if (m0 >= cnt) return;
    const int off = meta[8 + e];
    const int bx  = blockIdx.x;
    const int tid = threadIdx.x;

    __shared__ unsigned short As[128*64];   // 16 KB
    __shared__ unsigned short Bs[128*64];   // 16 KB

    f32x4 acc[4][4];
#pragma unroll
    for (int i = 0; i < 4; ++i)
#pragma unroll
        for (int j = 0; j < 4; ++j) acc[i][j] = (f32x4)0.0f;

    const int lane = tid & 63;
    const int wv   = tid >> 6;
    const char* a_src[4];
    const char* b_src[4];
#pragma unroll
    for (int i = 0; i < 4; ++i) {
        int lrow  = wv*32 + i*8 + (lane >> 3);
        int garow = off + m0 + lrow; if (garow > NPAIR-1) garow = NPAIR-1;
        a_src[i] = (const char*)h + (size_t)garow*(IDIM*2) + (lane & 7)*16;
        b_src[i] = (const char*)Wb +
                   ((size_t)e*CH2 + bx*128 + lrow)*(IDIM*2) + (lane & 7)*16;
    }
    const int base7 = (off + m0) & 7;

    const int wm = (wv >> 1) * 64, wn = (wv & 1) * 64;
    const int lr = lane & 15, lk = lane >> 4;

    const int NT = IDIM/64;   // 44
    for (int kt = 0; kt < NT; ++kt) {
        if (kt > 0) __syncthreads();
        ISSUE_A(kt);
        ISSUE_B(kt);
        __syncthreads();
        MFMA_STEP();
    }

#pragma unroll
    for (int mi = 0; mi < 4; ++mi)
#pragma unroll
        for (int nj = 0; nj < 4; ++nj) {
            f32x4 v = acc[mi][nj];
            int col = col0 + bx*128 + wn + nj*16 + lr;
#pragma unroll
            for (int r = 0; r < 4; ++r) {
                int row = wm + mi*16 + lk*4 + r;
                if (m0 + row < cnt) {
                    int p = meta[64 + off + m0 + row];
                    float w = tw[p];
                    yp[(size_t)p*DDIM + col] = v[r] * w;
                }
            }
        }
}

// ---------------- combine: out[t] = yp[2t] + yp[2t+1] ------------------------
__global__ void combine_kernel(const float* __restrict__ yp, float* __restrict__ out) {
    const int i = blockIdx.x * 256 + threadIdx.x;      // float4 index
    const int t = i >> 9, d = i & 511;
    const f32x4* a = (const f32x4*)yp;
    f32x4 va = a[(size_t)(t*2)*512 + d];
    f32x4 vb = a[(size_t)(t*2+1)*512 + d];
    ((f32x4*)out)[i] = va + vb;
}

extern "C" void kernel_launch(void* const* d_in, const int* in_sizes, int n_in,
                              void* d_out, int out_size, void* d_ws, size_t ws_size,
                              hipStream_t stream) {
    const float* x    = (const float*)d_in[0];
    const int*   ids  = (const int*)d_in[1];
    const float* tw   = (const float*)d_in[2];
    const int*   w13p = (const int*)d_in[3];
    const float* w13s = (const float*)d_in[4];
    const float* w13z = (const float*)d_in[5];
    const int*   w2p  = (const int*)d_in[6];
    const float* w2s  = (const float*)d_in[7];
    const float* w2z  = (const float*)d_in[8];
    float* out = (float*)d_out;

    char* ws = (char*)d_ws;
    int* meta = (int*)ws;
    unsigned short* Aall = (unsigned short*)(ws + OFF_A);
    unsigned short* gu   = (unsigned short*)(ws + OFF_GU);
    unsigned short* h    = (unsigned short*)(ws + OFF_H);
    float* yp            = (float*)(ws + OFF_YP);
    // bf16 weight-chunk overlays (stream-serial lifetimes; see layout comment)
    unsigned short* W13b = (unsigned short*)(ws + OFF_H);   // h+yp region, dead now
    unsigned short* W2b  = (unsigned short*)(ws + OFF_GU);  // gu region, dead after act

    route_kernel<<<1, 256, 0, stream>>>(ids, meta);
    gather_kernel<<<NPAIR, 256, 0, stream>>>(x, meta, Aall);
    for (int c = 0; c < NCH13; ++c) {
        deq13_kernel<<<dim3(CH13, NE), 256, 0, stream>>>(w13p, w13s, w13z, W13b, c*CH13);
        gemm1_kernel<<<dim3(CH13/128, NPAIR/128, NE), 256, 0, stream>>>(
            Aall, W13b, meta, gu, c*CH13);
    }
    act_kernel<<<NPAIR, 256, 0, stream>>>(gu, h);
    for (int c = 0; c < NCH2; ++c) {
        deq2_kernel<<<dim3(CH2, NE), 256, 0, stream>>>(w2p, w2s, w2z, W2b, c*CH2);
        gemm2_kernel<<<dim3(CH2/128, NPAIR/128, NE), 256, 0, stream>>>(
            h, W2b, tw, meta, yp, c*CH2);
    }
    combine_kernel<<<(T_TOK*DDIM/4)/256, 256, 0, stream>>>(yp, out);
}

// Round 9
// 494.769 us; speedup vs baseline: 1.0886x; 1.0886x over previous
//
#include <hip/hip_runtime.h>
#include <hip/hip_bf16.h>

// Problem constants (fixed by setup_inputs)
#define T_TOK 2048
#define DDIM  2048
#define IDIM  2816
#define NE    8
#define NPAIR (T_TOK*2)      // 4096 (token, k) pairs
#define GU_N  (2*IDIM)       // 5632

typedef __bf16  bf16x8 __attribute__((ext_vector_type(8)));
typedef float   f32x4  __attribute__((ext_vector_type(4)));
typedef int     int4v  __attribute__((ext_vector_type(4)));
typedef unsigned int uint2v __attribute__((ext_vector_type(2)));
typedef unsigned int uint4v __attribute__((ext_vector_type(4)));

// ws layout (bytes)
#define OFF_A   (64*1024)
#define OFF_GU  (OFF_A  + (size_t)NPAIR*DDIM*2)   // gu region 46.14 MB
#define OFF_H   (OFF_GU + (size_t)NPAIR*GU_N*2)   // h: 23 MB bf16 (pre-swizzled)
#define OFF_YP  (OFF_H  + (size_t)NPAIR*IDIM*2)   // yp: 32 MB f32
// Dense-weight overlays (R5-proven, lifetimes disjoint under stream order):
//   W13d (46.14 MB) at OFF_H  (h+yp region, dead during repack13/gemm1)
//   W2d  (23.07 MB) at OFF_GU (gu dead after act)
#define W13_DWORDS (NE*(size_t)GU_N*(DDIM/8))   // 11,534,336
#define W2_DWORDS  (NE*(size_t)DDIM*(IDIM/8))   //  5,767,168

__device__ __forceinline__ unsigned short f2bf(float f) {
    __hip_bfloat16 h = __float2bfloat16(f);
    return __builtin_bit_cast(unsigned short, h);
}
__device__ __forceinline__ float bf2f(unsigned short u) {
    unsigned int x = ((unsigned int)u) << 16;
    return __builtin_bit_cast(float, x);
}
__device__ __forceinline__ unsigned int pack2bf(float lo, float hi) {
    return ((unsigned int)f2bf(hi) << 16) | (unsigned int)f2bf(lo);
}
// async global->LDS, 16B per lane; LDS dest must be wave-uniform-base + lane*16
__device__ __forceinline__ void gload_lds16(const void* g, void* l) {
    __builtin_amdgcn_global_load_lds(
        (const __attribute__((address_space(1))) void*)g,
        (__attribute__((address_space(3))) void*)l, 16, 0, 0);
}

// ---------------- routing: stable compaction of 4096 pairs by expert ---------
// meta: [0..7]=cnt, [8..15]=off (exclusive prefix), [64..64+4095]=list (pair idx)
__global__ void route_kernel(const int* __restrict__ ids, int* __restrict__ meta) {
    __shared__ int histL[NE][256];
    __shared__ int totals[NE];
    __shared__ int offsS[NE];
    const int tid = threadIdx.x;
    for (int e = 0; e < NE; ++e) histL[e][tid] = 0;
    for (int j = 0; j < 16; ++j) {
        int id = ids[tid*16 + j];
        histL[id][tid]++;
    }
    __syncthreads();
    if (tid < NE) {
        int run = 0;
        for (int i = 0; i < 256; ++i) { int v = histL[tid][i]; histL[tid][i] = run; run += v; }
        totals[tid] = run;
    }
    __syncthreads();
    if (tid == 0) {
        int run = 0;
        for (int e = 0; e < NE; ++e) {
            offsS[e] = run;
            meta[e] = totals[e];
            meta[8+e] = run;
            run += totals[e];
        }
    }
    __syncthreads();
    for (int j = 0; j < 16; ++j) {
        int p = tid*16 + j;
        int id = ids[p];
        int local = histL[id][tid];
        histL[id][tid] = local + 1;
        meta[64 + offsS[id] + local] = p;
    }
}

// ---------------- gather: x rows -> compact PRE-SWIZZLED bf16 A matrix -------
// logical col-byte cb of row r stored at (cb&~127) | ((cb&127) ^ ((r&7)<<4))
__global__ void gather_kernel(const float* __restrict__ x, const int* __restrict__ meta,
                              unsigned short* __restrict__ Aall) {
    const int r = blockIdx.x;
    const int p = meta[64 + r];
    const int t = p >> 1;
    const int c = threadIdx.x * 8;
    const float4* src = (const float4*)(x + (size_t)t*DDIM + c);
    float4 f0 = src[0], f1 = src[1];
    unsigned short o[8];
    o[0]=f2bf(f0.x); o[1]=f2bf(f0.y); o[2]=f2bf(f0.z); o[3]=f2bf(f0.w);
    o[4]=f2bf(f1.x); o[5]=f2bf(f1.y); o[6]=f2bf(f1.z); o[7]=f2bf(f1.w);
    int cb  = c * 2;
    int cbs = (cb & ~127) | ((cb & 127) ^ ((r & 7) << 4));
    *(uint4v*)((char*)Aall + (size_t)r*(DDIM*2) + cbs) = *(uint4v*)o;
}

// ---------------- repack: 4x int32 (2 nibbles each) -> 1 uint32 (8 nibbles) --
// 4 dense words per thread: 64B coalesced in, 16B dwordx4 out.
__global__ void repack_kernel(const int* __restrict__ src,
                              unsigned int* __restrict__ dst, int nwords4) {
    const int i4 = blockIdx.x * 256 + threadIdx.x;
    if (i4 >= nwords4) return;
    const int4v* s = (const int4v*)(src + (size_t)i4*16);
    uint4v d;
#pragma unroll
    for (int q = 0; q < 4; ++q) {
        int4v p = s[q];
        d[q] = ((unsigned int)p[0] & 0xFFu)
             | (((unsigned int)p[1] & 0xFFu) << 8)
             | (((unsigned int)p[2] & 0xFFu) << 16)
             | (((unsigned int)p[3] & 0xFFu) << 24);
    }
    *(uint4v*)(dst + (size_t)i4*4) = d;
}

// ============ pipelined dequant-GEMM macros (shared by gemm1/gemm2) ==========
// 512 threads/block, 256x128 output tile, K-step 64.
// DEQ total work scales with N*K*(M/BM): BM=256 halves the B re-dequant count
// (16 m-blocks per B panel instead of 32). R2 proved this tile's correctness;
// its regression was purely the __launch_bounds__(512,4) 128-reg cap spilling
// the accumulator (VGPR 64 + 210MB scratch). Loose (512,2) bound fixes that;
// occupancy is LDS-bound: 80KB -> 2 blocks/CU = 16 waves/CU (R6 had 12).
// B staging: arow = tid>>2 (128 rows), aq = tid&3 (16 weights = 2 dense words)
#define LOADB(PK, SS, ZZ, KT)  do {                                        \
    PK = *(const uint2v*)(bgp + (size_t)(KT)*8);                           \
    int _g = (KT) >> 1;                                                    \
    SS = sp[_g]; ZZ = zp[_g];                                              \
} while (0)

// ISSUE_A: async-copy A K-slab KT into As[SEL]; 8 waves x 32 rows x 128B
#define ISSUE_A(SEL, KT) do {                                              \
    _Pragma("unroll")                                                      \
    for (int _i = 0; _i < 4; ++_i)                                         \
        gload_lds16(a_src[_i] + (size_t)(KT)*128,                          \
                    (char*)&As[SEL][0] + wv*4096 + _i*1024 + lane*16);     \
} while (0)

// DEQ: nibble-plane split -> byte extracts (v_cvt_f32_ubyte candidates);
// 2 dense words -> 16 bf16 (bit-identical arithmetic to R5/R6)
#define DEQ(PK, SS, ZZ, BWP) do {                                          \
    float _s = SS, _c = -(ZZ)*(SS);                                        \
    _Pragma("unroll")                                                      \
    for (int _q = 0; _q < 2; ++_q) {                                       \
        unsigned int _w  = PK[_q];                                         \
        unsigned int _lo = _w & 0x0F0F0F0Fu;                               \
        unsigned int _hi = (_w >> 4) & 0x0F0F0F0Fu;                        \
        _Pragma("unroll")                                                  \
        for (int _j = 0; _j < 4; ++_j) {                                   \
            float _flo = (float)((_lo >> (8*_j)) & 0xFFu);                 \
            float _fhi = (float)((_hi >> (8*_j)) & 0xFFu);                 \
            BWP[_q*4 + _j] = pack2bf(fmaf(_flo, _s, _c),                   \
                                     fmaf(_fhi, _s, _c));                  \
        }                                                                  \
    }                                                                      \
} while (0)

#define WRITE_BS(BWP) do {                                                 \
    _Pragma("unroll")                                                      \
    for (int _q = 0; _q < 2; ++_q) {                                       \
        int _cb  = aq*32 + _q*16;                                          \
        int _cbs = _cb ^ swzB;                                             \
        *(uint4v*)(&Bs[arow*64 + (_cbs >> 1)]) = *(uint4v*)(&BWP[_q*4]);   \
    }                                                                      \
} while (0)

// MFMA_STEP: 8 waves, wm = (wv>>1)*64 in [0,256), wn = (wv&1)*64 in [0,128)
#define MFMA_STEP(SEL) do {                                                \
    _Pragma("unroll")                                                      \
    for (int _kk = 0; _kk < 2; ++_kk) {                                    \
        bf16x8 _af[4], _bf[4];                                             \
        const int _kbyte = _kk*64 + lk*16;                                 \
        _Pragma("unroll")                                                  \
        for (int _mi = 0; _mi < 4; ++_mi) {                                \
            int _row = wm + _mi*16 + lr;                                   \
            int _b = _kbyte ^ (((_row + base7) & 7) << 4);                 \
            _af[_mi] = *(const bf16x8*)(&As[SEL][_row*64 + (_b >> 1)]);    \
        }                                                                  \
        _Pragma("unroll")                                                  \
        for (int _nj = 0; _nj < 4; ++_nj) {                                \
            int _row = wn + _nj*16 + lr;                                   \
            int _b = _kbyte ^ ((_row & 7) << 4);                           \
            _bf[_nj] = *(const bf16x8*)(&Bs[_row*64 + (_b >> 1)]);         \
        }                                                                  \
        _Pragma("unroll")                                                  \
        for (int _mi = 0; _mi < 4; ++_mi)                                  \
            _Pragma("unroll")                                              \
            for (int _nj = 0; _nj < 4; ++_nj)                              \
                acc[_mi][_nj] = __builtin_amdgcn_mfma_f32_16x16x32_bf16(   \
                    _af[_mi], _bf[_nj], acc[_mi][_nj], 0, 0, 0);           \
    }                                                                      \
} while (0)

// One K-step (R0/R6 proven order — best 2-barrier schedule tested R0..R8):
// barrier1; issue t+1 (A async->LDS, B->regs); dequant+commit t (covers the
// drain age at barrier2); barrier2; MFMA t. R8 proved removing the in-loop
// DEQ exposes raw load latency at barrier2 — the DEQ is latency insurance.
#define STEP(T, SELC, SELN, PKC, sC, zC, PKN, sN, zN) do {                 \
    if ((T) > 0) __syncthreads();                                          \
    int _ktn = (T)+1 < NT ? (T)+1 : NT-1;                                  \
    ISSUE_A(SELN, _ktn);                                                   \
    LOADB(PKN, sN, zN, _ktn);                                              \
    unsigned int _bw[8];                                                   \
    DEQ(PKC, sC, zC, _bw);                                                 \
    WRITE_BS(_bw);                                                         \
    __syncthreads();                                                       \
    MFMA_STEP(SELC);                                                       \
} while (0)

// ---------------- GEMM1: A[4096,2048]bf16 x W13d[e]^T (dense int4) -----------
// 256x128 tile, 512 threads, 80KB LDS -> 2 blocks/CU (16 waves).
__launch_bounds__(512, 2)
__global__ void gemm1_kernel(const unsigned short* __restrict__ Aall,
                             const unsigned int* __restrict__ wd,
                             const float* __restrict__ wsc,
                             const float* __restrict__ wzp,
                             const int* __restrict__ meta,
                             unsigned short* __restrict__ gu) {
    const int e   = blockIdx.z;
    const int cnt = meta[e];
    const int m0  = blockIdx.y * 256;
    if (m0 >= cnt) return;
    const int off = meta[8 + e];
    const int n0  = blockIdx.x * 128;
    const int tid = threadIdx.x;

    __shared__ unsigned short As[2][256*64];   // 64 KB
    __shared__ unsigned short Bs[128*64];      // 16 KB

    f32x4 acc[4][4];
#pragma unroll
    for (int i = 0; i < 4; ++i)
#pragma unroll
        for (int j = 0; j < 4; ++j) acc[i][j] = (f32x4)0.0f;

    // B staging mapping (dense words: 4 threads per B-row)
    const int arow  = tid >> 2;
    const int aq    = tid & 3;
    const int gbrow = n0 + arow;
    const unsigned int* bgp = wd + ((size_t)e*GU_N + gbrow)*(DDIM/8) + aq*2;
    const float* sp = wsc + ((size_t)e*GU_N + gbrow)*(DDIM/128);
    const float* zp = wzp + ((size_t)e*GU_N + gbrow)*(DDIM/128);
    const int swzB  = (arow & 7) << 4;

    // A async-copy mapping: 8 waves x 32 rows
    const int lane = tid & 63;
    const int wv   = tid >> 6;
    const char* a_src[4];
#pragma unroll
    for (int i = 0; i < 4; ++i) {
        int lrow  = wv*32 + i*8 + (lane >> 3);
        int garow = off + m0 + lrow; if (garow > NPAIR-1) garow = NPAIR-1;
        a_src[i] = (const char*)Aall + (size_t)garow*(DDIM*2) + (lane & 7)*16;
    }
    const int base7 = (off + m0) & 7;

    const int wm = (wv >> 1) * 64, wn = (wv & 1) * 64;
    const int lr = lane & 15, lk = lane >> 4;

    const int NT = DDIM/64;   // 32 (even)
    uint2v pkX, pkY;
    float sX, zX, sY, zY;

    ISSUE_A(0, 0);
    LOADB(pkX, sX, zX, 0);
    for (int kt = 0; kt < NT; kt += 2) {
        STEP(kt,   0, 1, pkX, sX, zX, pkY, sY, zY);
        STEP(kt+1, 1, 0, pkY, sY, zY, pkX, sX, zX);
    }

    // epilogue: C[m][n] lane map col=lane&15, row=(lane>>4)*4+reg (m89)
#pragma unroll
    for (int mi = 0; mi < 4; ++mi)
#pragma unroll
        for (int nj = 0; nj < 4; ++nj) {
            f32x4 v = acc[mi][nj];
            int col = n0 + wn + nj*16 + lr;
#pragma unroll
            for (int r = 0; r < 4; ++r) {
                int row = wm + mi*16 + lk*4 + r;
                if (m0 + row < cnt)
                    gu[(size_t)(off + m0 + row)*GU_N + col] = f2bf(v[r]);
            }
        }
}

// ---------------- activation: h = silu(g)*u, written PRE-SWIZZLED ------------
__global__ void act_kernel(const unsigned short* __restrict__ gu,
                           unsigned short* __restrict__ h) {
    const int r = blockIdx.x;
    for (int c = threadIdx.x; c < IDIM/8; c += 256) {
        uint4v g8 = *(const uint4v*)(&gu[(size_t)r*GU_N + c*8]);
        uint4v u8 = *(const uint4v*)(&gu[(size_t)r*GU_N + IDIM + c*8]);
        const unsigned short* gp = (const unsigned short*)&g8;
        const unsigned short* up = (const unsigned short*)&u8;
        unsigned short o[8];
#pragma unroll
        for (int j = 0; j < 8; ++j) {
            float g = bf2f(gp[j]), u = bf2f(up[j]);
            float sg = g / (1.0f + __expf(-g));
            o[j] = f2bf(sg * u);
        }
        int cb  = c * 16;
        int cbs = (cb & ~127) | ((cb & 127) ^ ((r & 7) << 4));
        *(uint4v*)((char*)h + (size_t)r*(IDIM*2) + cbs) = *(uint4v*)o;
    }
}

// ---------------- GEMM2: h[4096,2816]bf16 x W2d[e]^T (dense int4) ------------
__launch_bounds__(512, 2)
__global__ void gemm2_kernel(const unsigned short* __restrict__ h,
                             const unsigned int* __restrict__ wd,
                             const float* __restrict__ wsc,
                             const float* __restrict__ wzp,
                             const float* __restrict__ tw,
                             const int* __restrict__ meta,
                             float* __restrict__ yp) {
    const int e   = blockIdx.z;
    const int cnt = meta[e];
    const int m0  = blockIdx.y * 256;
    if (m0 >= cnt) return;
    const int off = meta[8 + e];
    const int n0  = blockIdx.x * 128;
    const int tid = threadIdx.x;

    __shared__ unsigned short As[2][256*64];   // 64 KB
    __shared__ unsigned short Bs[128*64];      // 16 KB

    f32x4 acc[4][4];
#pragma unroll
    for (int i = 0; i < 4; ++i)
#pragma unroll
        for (int j = 0; j < 4; ++j) acc[i][j] = (f32x4)0.0f;

    const int arow  = tid >> 2;
    const int aq    = tid & 3;
    const int gbrow = n0 + arow;
    const unsigned int* bgp = wd + ((size_t)e*DDIM + gbrow)*(IDIM/8) + aq*2;
    const float* sp = wsc + ((size_t)e*DDIM + gbrow)*(IDIM/128);
    const float* zp = wzp + ((size_t)e*DDIM + gbrow)*(IDIM/128);
    const int swzB  = (arow & 7) << 4;

    const int lane = tid & 63;
    const int wv   = tid >> 6;
    const char* a_src[4];
#pragma unroll
    for (int i = 0; i < 4; ++i) {
        int lrow  = wv*32 + i*8 + (lane >> 3);
        int garow = off + m0 + lrow; if (garow > NPAIR-1) garow = NPAIR-1;
        a_src[i] = (const char*)h + (size_t)garow*(IDIM*2) + (lane & 7)*16;
    }
    const int base7 = (off + m0) & 7;

    const int wm = (wv >> 1) * 64, wn = (wv & 1) * 64;
    const int lr = lane & 15, lk = lane >> 4;

    const int NT = IDIM/64;   // 44 (even)
    uint2v pkX, pkY;
    float sX, zX, sY, zY;

    ISSUE_A(0, 0);
    LOADB(pkX, sX, zX, 0);
    for (int kt = 0; kt < NT; kt += 2) {
        STEP(kt,   0, 1, pkX, sX, zX, pkY, sY, zY);
        STEP(kt+1, 1, 0, pkY, sY, zY, pkX, sX, zX);
    }

#pragma unroll
    for (int mi = 0; mi < 4; ++mi)
#pragma unroll
        for (int nj = 0; nj < 4; ++nj) {
            f32x4 v = acc[mi][nj];
            int col = n0 + wn + nj*16 + lr;
#pragma unroll
            for (int r = 0; r < 4; ++r) {
                int row = wm + mi*16 + lk*4 + r;
                if (m0 + row < cnt) {
                    int p = meta[64 + off + m0 + row];
                    float w = tw[p];
                    yp[(size_t)p*DDIM + col] = v[r] * w;
                }
            }
        }
}

// ---------------- combine: out[t] = yp[2t] + yp[2t+1] ------------------------
__global__ void combine_kernel(const float* __restrict__ yp, float* __restrict__ out) {
    const int i = blockIdx.x * 256 + threadIdx.x;      // float4 index
    const int t = i >> 9, d = i & 511;
    const f32x4* a = (const f32x4*)yp;
    f32x4 va = a[(size_t)(t*2)*512 + d];
    f32x4 vb = a[(size_t)(t*2+1)*512 + d];
    ((f32x4*)out)[i] = va + vb;
}

extern "C" void kernel_launch(void* const* d_in, const int* in_sizes, int n_in,
                              void* d_out, int out_size, void* d_ws, size_t ws_size,
                              hipStream_t stream) {
    const float* x    = (const float*)d_in[0];
    const int*   ids  = (const int*)d_in[1];
    const float* tw   = (const float*)d_in[2];
    const int*   w13p = (const int*)d_in[3];
    const float* w13s = (const float*)d_in[4];
    const float* w13z = (const float*)d_in[5];
    const int*   w2p  = (const int*)d_in[6];
    const float* w2s  = (const float*)d_in[7];
    const float* w2z  = (const float*)d_in[8];
    float* out = (float*)d_out;

    char* ws = (char*)d_ws;
    int* meta = (int*)ws;
    unsigned short* Aall = (unsigned short*)(ws + OFF_A);
    unsigned short* gu   = (unsigned short*)(ws + OFF_GU);
    unsigned short* h    = (unsigned short*)(ws + OFF_H);
    float* yp            = (float*)(ws + OFF_YP);
    // dense-weight overlays (lifetimes disjoint with the regions they borrow)
    unsigned int* W13d = (unsigned int*)(ws + OFF_H);
    unsigned int* W2d  = (unsigned int*)(ws + OFF_GU);

    route_kernel<<<1, 256, 0, stream>>>(ids, meta);
    gather_kernel<<<NPAIR, 256, 0, stream>>>(x, meta, Aall);
    repack_kernel<<<(int)(W13_DWORDS/1024), 256, 0, stream>>>(w13p, W13d, (int)(W13_DWORDS/4));
    gemm1_kernel<<<dim3(GU_N/128, NPAIR/256, NE), 512, 0, stream>>>(Aall, W13d, w13s, w13z, meta, gu);
    act_kernel<<<NPAIR, 256, 0, stream>>>(gu, h);
    repack_kernel<<<(int)(W2_DWORDS/1024), 256, 0, stream>>>(w2p, W2d, (int)(W2_DWORDS/4));
    gemm2_kernel<<<dim3(DDIM/128, NPAIR/256, NE), 512, 0, stream>>>(h, W2d, w2s, w2z, tw, meta, yp);
    combine_kernel<<<(T_TOK*DDIM/4)/256, 256, 0, stream>>>(yp, out);
}